// Round 15
// baseline (235.312 us; speedup 1.0000x reference)
//
#include <hip/hip_runtime.h>
#include <math.h>

// LSTM B=8192,T=512,IN=3,H=32,OUT=2 fp32.
// R23 = R22 + three idle-polish micro-cuts (schedule otherwise untouched):
// 1) Stagger re-tune: step shrank to ~856 cyc; half-step = 428 -> s_sleep(7)
//    (448 cyc) re-centers the two co-resident blocks' anti-phase.
// 2) 2x prefetch distance: consume-then-reload the SAME x-register triple
//    (U at even halves with TLOAD=t+3, V at odd with t+4) -> load->use gap
//    doubles to ~856 cyc, no extra regs, no copies, and the per-step tn
//    clamp vanishes (main loop unclamped; last 4 halves peeled, TLOAD=511).
// 3) Loads placed after xp-recompute in the slack (required by the
//    aliasing; slack shape otherwise identical).
// R22 established (rocprof ~182us): per SIMD-step 856 cyc = VALU 590
// (trans 448 = 28 x 16cyc floor + other 142) + MFMA 69 + idle 197. MFMA
// and VALU are additive within a SIMD (R9/R11) -> issue floor 659 cyc;
// we are at 77% of it, trans-dominated.
// Chassis (R13/R19/R21/R22, empirically tuned through 8 structural
// experiments): 4-wave blocks, 16 batches, single-pass MFMA acc=Ah*Bh+xp,
// adjacent-unit A-perm R(m)=32*(m&3)+8w+2*(m>>2)+c (acc_c[r]=gate r of
// unit 8w+2q+c, zero selects), pk-f32x2 gates w/ fused triple-rcp, cvt_pk
// pack, hi-only dbuf LDS [2][16][40], lgkm-only barrier (1/step), setprio
// choreography (prio0 slack / prio1 chain), block-parity stagger,
// grid 512 x 256 thr = 2 independent blocks/CU = 2 waves/SIMD.

namespace {
constexpr int   kT      = 512;
constexpr float kL2E    = 1.44269504088896340736f;
constexpr int   kStride = 40;   // ushorts per LDS row: 32 units + 8 pad
}

typedef __bf16 bf16x8 __attribute__((ext_vector_type(8)));
typedef float  f32x4  __attribute__((ext_vector_type(4)));
typedef float  f32x2  __attribute__((ext_vector_type(2)));
typedef unsigned int u32x4 __attribute__((ext_vector_type(4)));

union Frag {
    bf16x8 v;
    unsigned short u[8];
    unsigned int   d[4];
    u32x4          q4;
};

__device__ __forceinline__ unsigned short bf_rne(float f) {
    unsigned u = __float_as_uint(f);
    u += 0x7fffu + ((u >> 16) & 1u);
    return (unsigned short)(u >> 16);
}
__device__ __forceinline__ float bf_tof(unsigned short h) {
    return __uint_as_float((unsigned)h << 16);
}
__device__ __forceinline__ float fast_exp2(float v) { return __builtin_amdgcn_exp2f(v); }
__device__ __forceinline__ float fast_rcp(float v)  { return __builtin_amdgcn_rcpf(v); }

// v_cvt_pk_bf16_f32: dst = [lo16 = bf16_rne(a), hi16 = bf16_rne(b)]
__device__ __forceinline__ unsigned cvt_pk_bf16(float a, float b) {
    unsigned r;
    asm("v_cvt_pk_bf16_f32 %0, %1, %2" : "=v"(r) : "v"(a), "v"(b));
    return r;
}

__device__ __forceinline__ f32x2 fma2(f32x2 a, f32x2 b, f32x2 c) {
    return __builtin_elementwise_fma(a, b, c);
}
__device__ __forceinline__ f32x2 exp22(f32x2 v) {
    f32x2 r = {fast_exp2(v.x), fast_exp2(v.y)};
    return r;
}
__device__ __forceinline__ f32x2 rcp2(f32x2 v) {
    f32x2 r = {fast_rcp(v.x), fast_rcp(v.y)};
    return r;
}
__device__ __forceinline__ f32x2 sp2(float v) {
    f32x2 r = {v, v};
    return r;
}

// lgkmcnt-only barrier: ds ops drained, global loads stay in flight.
__device__ __forceinline__ void lgkm_barrier() {
    asm volatile("s_waitcnt lgkmcnt(0)" ::: "memory");
    __builtin_amdgcn_s_barrier();
    asm volatile("" ::: "memory");
}

#define MFMA16 __builtin_amdgcn_mfma_f32_16x16x32_bf16

extern "C" __global__ __launch_bounds__(256, 2)
void lstm_r23(const float* __restrict__ x,
              const float* __restrict__ W_ih,
              const float* __restrict__ W_hh,
              const float* __restrict__ b_ih,
              const float* __restrict__ b_hh,
              const float* __restrict__ W_fc,
              const float* __restrict__ b_fc,
              float* __restrict__ out) {
    const int tid  = threadIdx.x;
    const int lane = tid & 63;
    const int w    = tid >> 6;          // wave id 0..3
    const int n    = lane & 15;         // batch-within-block == B/D column
    const int q    = lane >> 4;         // k-quad / D row group
    const int bid  = blockIdx.x;
    const int batch = bid * 16 + n;

    // double-buffered h plane (hi only): [buf][batch][unit+pad]
    __shared__ __align__(16) unsigned short lds_h[2][16][kStride];

    // ---- A frags: chunk c, A row m -> W row R(m) = 32*(m&3)+8w+2*(m>>2)+c.
    // => acc_c[r] = gate r of unit u = 8w + 2q + c (adjacent units per lane).
    Frag Ah[2];
#pragma unroll
    for (int c = 0; c < 2; ++c) {
        const int   g = n & 3;
        const float s = (g == 2) ? -2.0f * kL2E : -kL2E;
        const int   R = 32 * g + 8 * w + 2 * (n >> 2) + c;
#pragma unroll
        for (int j = 0; j < 8; ++j) {
            Ah[c].u[j] = bf_rne(W_hh[R * 32 + 8 * q + j] * s);
        }
    }

    // ---- x-path constants: units (u0, u0+1) x 4 gates, f32x2-paired ----
    const int u0 = 8 * w + 2 * q;
    f32x2 xwp[4][3], xbp[4];
#pragma unroll
    for (int g = 0; g < 4; ++g) {
        const float s  = (g == 2) ? -2.0f * kL2E : -kL2E;
        const int   R0 = 32 * g + u0, R1 = R0 + 1;
#pragma unroll
        for (int k = 0; k < 3; ++k) {
            f32x2 wv = {W_ih[R0 * 3 + k] * s, W_ih[R1 * 3 + k] * s};
            xwp[g][k] = wv;
        }
        f32x2 bb = {(b_ih[R0] + b_hh[R0]) * s, (b_ih[R1] + b_hh[R1]) * s};
        xbp[g] = bb;
    }

    const float* xb = x + (size_t)batch * kT * 3;

    f32x2 cst = {0.f, 0.f};
    Frag Bh;
#pragma unroll
    for (int j = 0; j < 4; ++j) Bh.d[j] = 0;

    // prologue: xpC = XP(0); U = x(1); V = x(2)
    f32x4 xpC0, xpC1;
    {
        const float a0 = xb[0], a1 = xb[1], a2 = xb[2];
#pragma unroll
        for (int g = 0; g < 4; ++g) {
            f32x2 p = fma2(sp2(a0), xwp[g][0],
                      fma2(sp2(a1), xwp[g][1],
                      fma2(sp2(a2), xwp[g][2], xbp[g])));
            xpC0[g] = p.x;
            xpC1[g] = p.y;
        }
    }
    float U0 = xb[3], U1 = xb[4], U2 = xb[5];   // x(t+1) at even halves
    float V0 = xb[6], V1 = xb[7], V2 = xb[8];   // x(t+1) at odd halves

    // ---- block anti-phase stagger (one-time, ~half of the 856-cyc step) --
    if ((bid ^ (bid >> 8)) & 1) {
        __builtin_amdgcn_s_sleep(7);
    }

    __builtin_amdgcn_s_setprio(1);

    // step body: consumes held x regs (hx = x(t+1)), then RELOADS the same
    // triple with x[TLOAD] (consumed 2 halves later -> ~856-cyc cover).
#define STEP(TLOAD, BUF, hx0, hx1, hx2)                                      \
    {                                                                        \
        /* 2 MFMA single-pass, C carries exact fp32 xp (t=0: Bh=0) */        \
        f32x4 a0 = MFMA16(Ah[0].v, Bh.v, xpC0, 0, 0, 0);                     \
        f32x4 a1 = MFMA16(Ah[1].v, Bh.v, xpC1, 0, 0, 0);                     \
        /* slack: yield issue to the partner wave's critical path */         \
        __builtin_amdgcn_s_setprio(0);                                       \
        _Pragma("unroll")                                                    \
        for (int g = 0; g < 4; ++g) {                                        \
            f32x2 p = fma2(sp2(hx0), xwp[g][0],                              \
                      fma2(sp2(hx1), xwp[g][1],                              \
                      fma2(sp2(hx2), xwp[g][2], xbp[g])));                   \
            xpC0[g] = p.x;                                                   \
            xpC1[g] = p.y;                                                   \
        }                                                                    \
        hx0 = xb[(TLOAD) * 3 + 0];                                           \
        hx1 = xb[(TLOAD) * 3 + 1];                                           \
        hx2 = xb[(TLOAD) * 3 + 2];                                           \
        __builtin_amdgcn_s_setprio(1);                                       \
        /* gates, f32x2 over (u0, u0+1): acc_c[r] = gate r */                \
        const f32x2 one = {1.f, 1.f};                                        \
        f32x2 P0 = {a0[0], a1[0]};                                           \
        f32x2 P1 = {a0[1], a1[1]};                                           \
        f32x2 P2 = {a0[2], a1[2]};                                           \
        f32x2 P3 = {a0[3], a1[3]};                                           \
        f32x2 Ei = exp22(P0);                                                \
        f32x2 Ef = exp22(P1);                                                \
        f32x2 Eg = exp22(P2);                                                \
        f32x2 Eo = exp22(P3);                                                \
        f32x2 pf  = one + Ef;                                                \
        f32x2 pi  = one + Ei;                                                \
        f32x2 pg  = one + Eg;                                                \
        f32x2 tig = pi * pg;                                                 \
        f32x2 den = tig * pf;                                                \
        f32x2 num = fma2(cst, tig, (one - Eg) * pf);                         \
        f32x2 c   = num * rcp2(den);                                         \
        cst = c;                                                             \
        f32x2 ca  = c * sp2(-2.0f * kL2E);                                   \
        f32x2 Ec  = exp22(ca);                                               \
        Ec.x = fminf(Ec.x, 1e30f);                                           \
        Ec.y = fminf(Ec.y, 1e30f);                                           \
        f32x2 od  = (one + Eo) * (one + Ec);                                 \
        f32x2 h2  = (one - Ec) * rcp2(od);                                   \
        /* pack + exchange */                                                \
        const unsigned hh = cvt_pk_bf16(h2.x, h2.y);                         \
        *(unsigned*)&lds_h[BUF][n][u0] = hh;                                 \
        lgkm_barrier();                                                      \
        Bh.q4 = *(const u32x4*)&lds_h[BUF][n][8 * q];                        \
    }

    // main: t = 0..506 (pairs); invariant before pair t: U=x(t+1), V=x(t+2)
    for (int t = 0; t < 508; t += 2) {
        STEP(t + 3, 0, U0, U1, U2)
        STEP(t + 4, 1, V0, V1, V2)
    }
    // peel halves 508..511 (loads clamped to x(511); late xp outputs are
    // either x(511)-correct or discarded garbage for t=511)
    STEP(511, 0, U0, U1, U2)
    STEP(511, 1, V0, V1, V2)
    STEP(511, 0, U0, U1, U2)
    STEP(511, 1, V0, V1, V2)
#undef STEP

    // ---- epilogue (wave 0): h(511) is in lds buf 1 ----
    if (w == 0) {
        Frag Hh;
        Hh.q4 = *(const u32x4*)&lds_h[1][n][8 * q];
        float s0 = 0.f, s1 = 0.f;
#pragma unroll
        for (int j = 0; j < 8; ++j) {
            const float hv = bf_tof(Hh.u[j]);
            const int   u  = 8 * q + j;
            s0 = fmaf(hv, W_fc[u], s0);
            s1 = fmaf(hv, W_fc[32 + u], s1);
        }
        s0 += __shfl_xor(s0, 16, 64); s1 += __shfl_xor(s1, 16, 64);
        s0 += __shfl_xor(s0, 32, 64); s1 += __shfl_xor(s1, 32, 64);
        if (lane < 16) {
            out[(size_t)batch * 2 + 0] = s0 + b_fc[0];
            out[(size_t)batch * 2 + 1] = s1 + b_fc[1];
        }
    }
}

extern "C" void kernel_launch(void* const* d_in, const int* in_sizes, int n_in,
                              void* d_out, int out_size, void* d_ws, size_t ws_size,
                              hipStream_t stream) {
    const float* x    = (const float*)d_in[0];
    const float* W_ih = (const float*)d_in[1];
    const float* W_hh = (const float*)d_in[2];
    const float* b_ih = (const float*)d_in[3];
    const float* b_hh = (const float*)d_in[4];
    const float* W_fc = (const float*)d_in[5];
    const float* b_fc = (const float*)d_in[6];
    float* out = (float*)d_out;

    const int batch = in_sizes[0] / (kT * 3);   // 8192
    dim3 grid(batch / 16);                      // 512 blocks of 4 waves
    dim3 block(256);                            // -> 2 blocks/CU, 2 waves/SIMD
    hipLaunchKernelGGL(lstm_r23, grid, block, 0, stream,
                       x, W_ih, W_hh, b_ih, b_hh, W_fc, b_fc, out);
}

// Round 16
// 234.944 us; speedup vs baseline: 1.0016x; 1.0016x over previous
//
#include <hip/hip_runtime.h>
#include <math.h>

// LSTM B=8192,T=512,IN=3,H=32,OUT=2 fp32.
// R24 = R22 byte-identical (revert of R23's neutral-to-negative riders).
// R23 post-mortem: stagger retune + 2x prefetch distance + load placement
// were aggregate -3%; the ~197cyc/step residual idle is structural
// (barrier + ~500cyc dep chain vs 856cyc period, 2 waves/SIMD).
// R22 (best, bench 233.5us, rocprof ~182-187): per SIMD-step 856 cyc =
// VALU 590 (trans 448 = 28 x 16cyc quarter-rate floor: 5 exp2 + 2 rcp per
// unit is the algebraic minimum + other 142) + MFMA 69 + idle 197 = 77% of
// the additive issue floor. Session ladder: 405 (R8) -> 272 (R13 unit-split)
// -> 225 (R19 drop h-lo + lgkm barrier) -> 205 (R21 drop W-lo) -> 182 (R22
// setprio choreography + unroll-2). Structural alternatives refuted:
// replication (R9-R11), 4 waves scalar (R14), dual-stream 1w (R15/R16),
// criss-cross 2w (R17/R18), post-barrier reorder (R20), idle polish (R23).
// Chassis: 4-wave blocks, 16 batches, single-pass MFMA acc=Ah*Bh+xp
// (adjacent-unit A-perm R(m)=32*(m&3)+8w+2*(m>>2)+c -> acc_c[r] = gate r
// of unit 8w+2q+c, zero selects), pk-f32x2 gates w/ fused triple-rcp,
// cvt_pk pack, hi-only dbuf LDS [2][16][40], lgkm-only barrier (1/step),
// setprio (prio0 slack / prio1 chain), block-parity s_sleep(8) stagger,
// grid 512 x 256 thr = 2 independent blocks/CU = 2 waves/SIMD.

namespace {
constexpr int   kT      = 512;
constexpr float kL2E    = 1.44269504088896340736f;
constexpr int   kStride = 40;   // ushorts per LDS row: 32 units + 8 pad
}

typedef __bf16 bf16x8 __attribute__((ext_vector_type(8)));
typedef float  f32x4  __attribute__((ext_vector_type(4)));
typedef float  f32x2  __attribute__((ext_vector_type(2)));
typedef unsigned int u32x4 __attribute__((ext_vector_type(4)));

union Frag {
    bf16x8 v;
    unsigned short u[8];
    unsigned int   d[4];
    u32x4          q4;
};

__device__ __forceinline__ unsigned short bf_rne(float f) {
    unsigned u = __float_as_uint(f);
    u += 0x7fffu + ((u >> 16) & 1u);
    return (unsigned short)(u >> 16);
}
__device__ __forceinline__ float bf_tof(unsigned short h) {
    return __uint_as_float((unsigned)h << 16);
}
__device__ __forceinline__ float fast_exp2(float v) { return __builtin_amdgcn_exp2f(v); }
__device__ __forceinline__ float fast_rcp(float v)  { return __builtin_amdgcn_rcpf(v); }

// v_cvt_pk_bf16_f32: dst = [lo16 = bf16_rne(a), hi16 = bf16_rne(b)]
__device__ __forceinline__ unsigned cvt_pk_bf16(float a, float b) {
    unsigned r;
    asm("v_cvt_pk_bf16_f32 %0, %1, %2" : "=v"(r) : "v"(a), "v"(b));
    return r;
}

__device__ __forceinline__ f32x2 fma2(f32x2 a, f32x2 b, f32x2 c) {
    return __builtin_elementwise_fma(a, b, c);
}
__device__ __forceinline__ f32x2 exp22(f32x2 v) {
    f32x2 r = {fast_exp2(v.x), fast_exp2(v.y)};
    return r;
}
__device__ __forceinline__ f32x2 rcp2(f32x2 v) {
    f32x2 r = {fast_rcp(v.x), fast_rcp(v.y)};
    return r;
}
__device__ __forceinline__ f32x2 sp2(float v) {
    f32x2 r = {v, v};
    return r;
}

// lgkmcnt-only barrier: ds ops drained, global loads stay in flight.
__device__ __forceinline__ void lgkm_barrier() {
    asm volatile("s_waitcnt lgkmcnt(0)" ::: "memory");
    __builtin_amdgcn_s_barrier();
    asm volatile("" ::: "memory");
}

#define MFMA16 __builtin_amdgcn_mfma_f32_16x16x32_bf16

extern "C" __global__ __launch_bounds__(256, 2)
void lstm_r24(const float* __restrict__ x,
              const float* __restrict__ W_ih,
              const float* __restrict__ W_hh,
              const float* __restrict__ b_ih,
              const float* __restrict__ b_hh,
              const float* __restrict__ W_fc,
              const float* __restrict__ b_fc,
              float* __restrict__ out) {
    const int tid  = threadIdx.x;
    const int lane = tid & 63;
    const int w    = tid >> 6;          // wave id 0..3
    const int n    = lane & 15;         // batch-within-block == B/D column
    const int q    = lane >> 4;         // k-quad / D row group
    const int bid  = blockIdx.x;
    const int batch = bid * 16 + n;

    // double-buffered h plane (hi only): [buf][batch][unit+pad]
    __shared__ __align__(16) unsigned short lds_h[2][16][kStride];

    // ---- A frags: chunk c, A row m -> W row R(m) = 32*(m&3)+8w+2*(m>>2)+c.
    // => acc_c[r] = gate r of unit u = 8w + 2q + c (adjacent units per lane).
    Frag Ah[2];
#pragma unroll
    for (int c = 0; c < 2; ++c) {
        const int   g = n & 3;
        const float s = (g == 2) ? -2.0f * kL2E : -kL2E;
        const int   R = 32 * g + 8 * w + 2 * (n >> 2) + c;
#pragma unroll
        for (int j = 0; j < 8; ++j) {
            Ah[c].u[j] = bf_rne(W_hh[R * 32 + 8 * q + j] * s);
        }
    }

    // ---- x-path constants: units (u0, u0+1) x 4 gates, f32x2-paired ----
    const int u0 = 8 * w + 2 * q;
    f32x2 xwp[4][3], xbp[4];
#pragma unroll
    for (int g = 0; g < 4; ++g) {
        const float s  = (g == 2) ? -2.0f * kL2E : -kL2E;
        const int   R0 = 32 * g + u0, R1 = R0 + 1;
#pragma unroll
        for (int k = 0; k < 3; ++k) {
            f32x2 wv = {W_ih[R0 * 3 + k] * s, W_ih[R1 * 3 + k] * s};
            xwp[g][k] = wv;
        }
        f32x2 bb = {(b_ih[R0] + b_hh[R0]) * s, (b_ih[R1] + b_hh[R1]) * s};
        xbp[g] = bb;
    }

    const float* xb = x + (size_t)batch * kT * 3;

    f32x2 cst = {0.f, 0.f};
    Frag Bh;
#pragma unroll
    for (int j = 0; j < 4; ++j) Bh.d[j] = 0;

    // prologue: xpC = XP(0); xcA = x(1)
    f32x4 xpC0, xpC1;
    {
        const float a0 = xb[0], a1 = xb[1], a2 = xb[2];
#pragma unroll
        for (int g = 0; g < 4; ++g) {
            f32x2 p = fma2(sp2(a0), xwp[g][0],
                      fma2(sp2(a1), xwp[g][1],
                      fma2(sp2(a2), xwp[g][2], xbp[g])));
            xpC0[g] = p.x;
            xpC1[g] = p.y;
        }
    }
    float xcA0 = xb[3], xcA1 = xb[4], xcA2 = xb[5];  // x(t+1), even steps
    float xcB0 = 0.f,   xcB1 = 0.f,   xcB2 = 0.f;    // x(t+1), odd steps

    // ---- block anti-phase stagger (one-time, ~half step) ----
    if ((bid ^ (bid >> 8)) & 1) {
        __builtin_amdgcn_s_sleep(8);
    }

    __builtin_amdgcn_s_setprio(1);

    // step body: consumes held x(t+1) regs (hx), loads x(t+2) into (lx).
#define STEP(T, BUF, hx0, hx1, hx2, lx0, lx1, lx2)                          \
    {                                                                        \
        /* 2 MFMA single-pass, C carries exact fp32 xp (t=0: Bh=0) */        \
        f32x4 a0 = MFMA16(Ah[0].v, Bh.v, xpC0, 0, 0, 0);                     \
        f32x4 a1 = MFMA16(Ah[1].v, Bh.v, xpC1, 0, 0, 0);                     \
        /* slack shadow: yield issue to the partner wave's critical path */  \
        __builtin_amdgcn_s_setprio(0);                                       \
        const int tn = ((T) + 2 < kT) ? (T) + 2 : kT - 1;                    \
        lx0 = xb[tn * 3 + 0];                                                \
        lx1 = xb[tn * 3 + 1];                                                \
        lx2 = xb[tn * 3 + 2];                                                \
        _Pragma("unroll")                                                    \
        for (int g = 0; g < 4; ++g) {                                        \
            f32x2 p = fma2(sp2(hx0), xwp[g][0],                              \
                      fma2(sp2(hx1), xwp[g][1],                              \
                      fma2(sp2(hx2), xwp[g][2], xbp[g])));                   \
            xpC0[g] = p.x;                                                   \
            xpC1[g] = p.y;                                                   \
        }                                                                    \
        __builtin_amdgcn_s_setprio(1);                                       \
        /* gates, f32x2 over (u0, u0+1): acc_c[r] = gate r */                \
        const f32x2 one = {1.f, 1.f};                                        \
        f32x2 P0 = {a0[0], a1[0]};                                           \
        f32x2 P1 = {a0[1], a1[1]};                                           \
        f32x2 P2 = {a0[2], a1[2]};                                           \
        f32x2 P3 = {a0[3], a1[3]};                                           \
        f32x2 Ei = exp22(P0);                                                \
        f32x2 Ef = exp22(P1);                                                \
        f32x2 Eg = exp22(P2);                                                \
        f32x2 Eo = exp22(P3);                                                \
        f32x2 pf  = one + Ef;                                                \
        f32x2 pi  = one + Ei;                                                \
        f32x2 pg  = one + Eg;                                                \
        f32x2 tig = pi * pg;                                                 \
        f32x2 den = tig * pf;                                                \
        f32x2 num = fma2(cst, tig, (one - Eg) * pf);                         \
        f32x2 c   = num * rcp2(den);                                         \
        cst = c;                                                             \
        f32x2 ca  = c * sp2(-2.0f * kL2E);                                   \
        f32x2 Ec  = exp22(ca);                                               \
        Ec.x = fminf(Ec.x, 1e30f);                                           \
        Ec.y = fminf(Ec.y, 1e30f);                                           \
        f32x2 od  = (one + Eo) * (one + Ec);                                 \
        f32x2 h2  = (one - Ec) * rcp2(od);                                   \
        /* pack + exchange */                                                \
        const unsigned hh = cvt_pk_bf16(h2.x, h2.y);                         \
        *(unsigned*)&lds_h[BUF][n][u0] = hh;                                 \
        lgkm_barrier();                                                      \
        Bh.q4 = *(const u32x4*)&lds_h[BUF][n][8 * q];                        \
    }

    for (int t = 0; t < kT; t += 2) {
        STEP(t,     0, xcA0, xcA1, xcA2, xcB0, xcB1, xcB2)
        STEP(t + 1, 1, xcB0, xcB1, xcB2, xcA0, xcA1, xcA2)
    }
#undef STEP

    // ---- epilogue (wave 0): h(511) is in lds buf 1 ----
    if (w == 0) {
        Frag Hh;
        Hh.q4 = *(const u32x4*)&lds_h[1][n][8 * q];
        float s0 = 0.f, s1 = 0.f;
#pragma unroll
        for (int j = 0; j < 8; ++j) {
            const float hv = bf_tof(Hh.u[j]);
            const int   u  = 8 * q + j;
            s0 = fmaf(hv, W_fc[u], s0);
            s1 = fmaf(hv, W_fc[32 + u], s1);
        }
        s0 += __shfl_xor(s0, 16, 64); s1 += __shfl_xor(s1, 16, 64);
        s0 += __shfl_xor(s0, 32, 64); s1 += __shfl_xor(s1, 32, 64);
        if (lane < 16) {
            out[(size_t)batch * 2 + 0] = s0 + b_fc[0];
            out[(size_t)batch * 2 + 1] = s1 + b_fc[1];
        }
    }
}

extern "C" void kernel_launch(void* const* d_in, const int* in_sizes, int n_in,
                              void* d_out, int out_size, void* d_ws, size_t ws_size,
                              hipStream_t stream) {
    const float* x    = (const float*)d_in[0];
    const float* W_ih = (const float*)d_in[1];
    const float* W_hh = (const float*)d_in[2];
    const float* b_ih = (const float*)d_in[3];
    const float* b_hh = (const float*)d_in[4];
    const float* W_fc = (const float*)d_in[5];
    const float* b_fc = (const float*)d_in[6];
    float* out = (float*)d_out;

    const int batch = in_sizes[0] / (kT * 3);   // 8192
    dim3 grid(batch / 16);                      // 512 blocks of 4 waves
    dim3 block(256);                            // -> 2 blocks/CU, 2 waves/SIMD
    hipLaunchKernelGGL(lstm_r24, grid, block, 0, stream,
                       x, W_ih, W_hh, b_ih, b_hh, W_fc, b_fc, out);
}